// Round 8
// baseline (331.556 us; speedup 1.0000x reference)
//
#include <hip/hip_runtime.h>

#define N 2048
#define LEV 256
#define KS 16

typedef __attribute__((ext_vector_type(8))) short bfx8;
typedef __attribute__((ext_vector_type(4))) float fx4;
typedef unsigned short u16;
typedef unsigned int u32;

static const size_t NN = (size_t)N * N;

__device__ inline u16 bf16_rne(float f) {
    u32 u = __builtin_bit_cast(u32, f);
    u32 r = (u + 0x7FFFu + ((u >> 16) & 1u)) >> 16;
    return (u16)r;
}
__device__ inline float bf16_f(u16 h) {
    u32 u = ((u32)h) << 16;
    return __builtin_bit_cast(float, u);
}

// async global->LDS, 16B per lane. LDS dest = wave-uniform base + lane*16.
#define GLDS16(gp, lp) __builtin_amdgcn_global_load_lds( \
    (const __attribute__((address_space(1))) void*)(uintptr_t)(gp), \
    (__attribute__((address_space(3))) void*)(u32)(uintptr_t)(lp), 16, 0, 0)

// sum over the 4 lanes of each quad (lane^1 then lane^2), VALU-only via DPP.
__device__ inline float qadd(float x) {
#if __has_builtin(__builtin_amdgcn_mov_dpp)
    int a = __builtin_amdgcn_mov_dpp(__builtin_bit_cast(int, x), 0xB1, 0xF, 0xF, true);
    float y = x + __builtin_bit_cast(float, a);
    int b = __builtin_amdgcn_mov_dpp(__builtin_bit_cast(int, y), 0x4E, 0xF, 0xF, true);
    return y + __builtin_bit_cast(float, b);
#else
    float y = x + __shfl_xor(x, 1);
    return y + __shfl_xor(y, 2);
#endif
}

// ---------------------------------------------------------------------------
// build RT = (U_{L-1}...U_0)^T, FOUR columns per wave (sel/O shared across
// columns -> 4 independent chains quadruple ILP per wave). Single wave ->
// DS program order, no barriers. Output row-major RT (coalesced).
// ---------------------------------------------------------------------------
__global__ __launch_bounds__(64)
void build_right_k(const float* __restrict__ O_all, const int* __restrict__ sel,
                   float* __restrict__ RT) {
    __shared__ float x[4][2052];     // 2052: bank-decorrelated bases
    const int lane = threadIdx.x;
    const int i    = lane >> 2;      // row 0..15
    const int kg   = lane & 3;       // k-quarter 0..3
    const int col0 = blockIdx.x * 4;

    const float4 z = make_float4(0.f, 0.f, 0.f, 0.f);
    #pragma unroll
    for (int c = 0; c < 4; ++c)
        #pragma unroll
        for (int q = 0; q < 8; ++q)
            *(float4*)&x[c][q * 256 + lane * 4] = z;
    if (lane < 4) x[lane][col0 + lane] = 1.0f;   // e_{col0+c}; in-order DS

    float4 o = *(const float4*)(O_all + i * KS + kg * 4);
    int4   g = *(const int4*)(sel + kg * 4);
    int    wi = sel[i];

    for (int l = 0; l < LEV; ++l) {
        float4 on; int4 gn; int win;
        if (l + 1 < LEV) {           // prefetch next level (uniform branch)
            const size_t ob = (size_t)(l + 1) * (KS * KS);
            on  = *(const float4*)(O_all + ob + i * KS + kg * 4);
            gn  = *(const int4*)(sel + (l + 1) * KS + kg * 4);
            win = sel[(l + 1) * KS + i];
        } else { on = o; gn = g; win = wi; }

        float p0 = o.x * x[0][g.x] + o.y * x[0][g.y] + o.z * x[0][g.z] + o.w * x[0][g.w];
        float p1 = o.x * x[1][g.x] + o.y * x[1][g.y] + o.z * x[1][g.z] + o.w * x[1][g.w];
        float p2 = o.x * x[2][g.x] + o.y * x[2][g.y] + o.z * x[2][g.z] + o.w * x[2][g.w];
        float p3 = o.x * x[3][g.x] + o.y * x[3][g.y] + o.z * x[3][g.z] + o.w * x[3][g.w];
        p0 = qadd(p0); p1 = qadd(p1); p2 = qadd(p2); p3 = qadd(p3);
        if (kg == 0) { x[0][wi] = p0; x[1][wi] = p1; x[2][wi] = p2; x[3][wi] = p3; }

        o = on; g = gn; wi = win;
    }

    #pragma unroll
    for (int c = 0; c < 4; ++c)
        #pragma unroll
        for (int q = 0; q < 8; ++q)
            *(float4*)&RT[(size_t)(col0 + c) * N + q * 256 + lane * 4] =
                *(const float4*)&x[c][q * 256 + lane * 4];
}

// ---------------------------------------------------------------------------
// split fp32 matrix -> bf16 hi/lo planes (streaming)
// ---------------------------------------------------------------------------
__global__ __launch_bounds__(256)
void split_plain_k(const float* __restrict__ src, u16* __restrict__ dh) {
    u16* dl = dh + NN;
    size_t p = ((size_t)blockIdx.x * 256 + threadIdx.x) * 8;
    float4 v0 = *(const float4*)(src + p);
    float4 v1 = *(const float4*)(src + p + 4);
    float vv[8] = {v0.x, v0.y, v0.z, v0.w, v1.x, v1.y, v1.z, v1.w};
    bfx8 hs, ls;
    #pragma unroll
    for (int i = 0; i < 8; ++i) {
        u16 h = bf16_rne(vv[i]);
        hs[i] = (short)h;
        ls[i] = (short)bf16_rne(vv[i] - bf16_f(h));
    }
    *(bfx8*)(dh + p) = hs;
    *(bfx8*)(dl + p) = ls;
}

// ---------------------------------------------------------------------------
// From RT (= R^T row-major): R2 = split(R), RT2 = split(RT), R fp32 row-major.
// ---------------------------------------------------------------------------
__global__ __launch_bounds__(256)
void split_rt_k(const float* __restrict__ RT, u16* __restrict__ r2h,
                u16* __restrict__ rth, float* __restrict__ Rrm) {
    __shared__ float t[64][65];
    u16* r2l = r2h + NN;
    u16* rtl = rth + NN;
    const int r0 = (blockIdx.x >> 5) * 64, c0 = (blockIdx.x & 31) * 64;
    #pragma unroll
    for (int i = 0; i < 16; ++i) {
        int q = i * 256 + threadIdx.x;
        int rr = q >> 6, cc = q & 63;
        t[rr][cc] = RT[(size_t)(r0 + rr) * N + c0 + cc];
    }
    __syncthreads();
    #pragma unroll
    for (int i = 0; i < 16; ++i) {
        int q = i * 256 + threadIdx.x;
        int rr = q >> 6, cc = q & 63;
        float v = t[rr][cc];                        // RT[r0+rr][c0+cc]
        u16 h = bf16_rne(v);
        size_t po = (size_t)(r0 + rr) * N + c0 + cc;
        rth[po] = h;                                // split(RT)
        rtl[po] = bf16_rne(v - bf16_f(h));
        float w = t[cc][rr];                        // = R[c0+rr][r0+cc]
        u16 h2 = bf16_rne(w);
        size_t pt = (size_t)(c0 + rr) * N + r0 + cc;
        r2h[pt] = h2;                               // split(R)
        r2l[pt] = bf16_rne(w - bf16_f(h2));
        Rrm[pt] = w;                                // R fp32 (output slot)
    }
}

// ---------------------------------------------------------------------------
// D fp32 = hi + lo
// ---------------------------------------------------------------------------
__global__ __launch_bounds__(256)
void unsplit_k(const u16* __restrict__ hi, float* __restrict__ dst) {
    const u16* lo = hi + NN;
    size_t p = ((size_t)blockIdx.x * 256 + threadIdx.x) * 8;
    bfx8 hs = *(const bfx8*)(hi + p);
    bfx8 ls = *(const bfx8*)(lo + p);
    float4 o0, o1;
    o0.x = bf16_f((u16)hs[0]) + bf16_f((u16)ls[0]);
    o0.y = bf16_f((u16)hs[1]) + bf16_f((u16)ls[1]);
    o0.z = bf16_f((u16)hs[2]) + bf16_f((u16)ls[2]);
    o0.w = bf16_f((u16)hs[3]) + bf16_f((u16)ls[3]);
    o1.x = bf16_f((u16)hs[4]) + bf16_f((u16)ls[4]);
    o1.y = bf16_f((u16)hs[5]) + bf16_f((u16)ls[5]);
    o1.z = bf16_f((u16)hs[6]) + bf16_f((u16)ls[6]);
    o1.w = bf16_f((u16)hs[7]) + bf16_f((u16)ls[7]);
    *(float4*)(dst + p)     = o0;
    *(float4*)(dst + p + 4) = o1;
}

// ---------------------------------------------------------------------------
// C = X * Y^T via 3-term bf16 split MFMA.
// global_load_lds double-buffer, both-sides XOR swizzle, 128x128 tile.
// SYMOUT: C symmetric -> grid = 136 upper-tri blocks; off-diag blocks also
// write the mirrored tile via an LDS bounce (exactly symmetric output).
// ---------------------------------------------------------------------------
template<int MASKED, int OMODE, int SYMOUT>
__global__ __launch_bounds__(256)
void gemm_bf3(const u16* __restrict__ Xp, const u16* __restrict__ Yp,
              float* __restrict__ Cf, u16* __restrict__ Cs,
              const int* __restrict__ wav, int Lw) {
    __shared__ __align__(16) u16 sm[2][4][8192];   // 128 KB; epilogue reuse
    __shared__ float rowf[128], colf[128];

    const int tid = threadIdx.x;
    int bx, by;
    if (SYMOUT) {
        // 136 blocks = 8 XCD chunks of 17 (bijective)
        int swz = (blockIdx.x & 7) * 17 + (blockIdx.x >> 3);
        int t = swz, r = 0;
        #pragma unroll 1
        while (t >= 16 - r) { t -= 16 - r; ++r; }
        by = r; bx = r + t;                        // by <= bx
    } else {
        const int swz = ((blockIdx.x & 7) << 5) | (blockIdx.x >> 3);
        bx = swz & 15;
        by = swz >> 4;
    }
    const int i0 = by * 128, j0 = bx * 128;
    const int lane = tid & 63, w = tid >> 6;
    const int wm = (w >> 1) * 64, wn = (w & 1) * 64;
    const int fr = lane & 15;

    if (MASKED) {
        if (tid < 128) rowf[tid] = 1.0f; else colf[tid - 128] = 1.0f;
        __syncthreads();
        for (int t = tid; t < Lw; t += 256) {
            int wv = wav[t];
            int dr = wv - i0; if (0 <= dr && dr < 128) rowf[dr] = 0.0f;
            int dc = wv - j0; if (0 <= dc && dc < 128) colf[dc] = 0.0f;
        }
    }

    fx4 acc[4][4];
    #pragma unroll
    for (int m = 0; m < 4; ++m)
        #pragma unroll
        for (int n = 0; n < 4; ++n)
            acc[m][n] = (fx4)0.0f;

    const u16* Xh = Xp; const u16* Xl = Xp + NN;
    const u16* Yh = Yp; const u16* Yl = Yp + NN;

    const int rl   = lane >> 3;
    const int gcol = ((lane & 7) ^ rl) << 3;
    const int wq   = w * 1024;

    #define STAGE(buf, kt) { \
        const int k0s = (kt) * 64; \
        char* lb0 = (char*)&sm[buf][0][0] + wq; \
        _Pragma("unroll") \
        for (int q = 0; q < 4; ++q) { \
            const int row = q * 32 + w * 8 + rl; \
            const size_t xo = (size_t)(i0 + row) * N + k0s + gcol; \
            const size_t yo = (size_t)(j0 + row) * N + k0s + gcol; \
            GLDS16(Xh + xo, lb0 + q * 4096); \
            GLDS16(Xl + xo, lb0 + 16384 + q * 4096); \
            GLDS16(Yh + yo, lb0 + 32768 + q * 4096); \
            GLDS16(Yl + yo, lb0 + 49152 + q * 4096); \
        } }

    const int kq  = (lane >> 4) << 4;
    const int frx = (fr & 7) << 4;

    #define COMPUTE(buf) { \
        const char* base = (const char*)&sm[buf][0][0]; \
        _Pragma("unroll") \
        for (int s = 0; s < 2; ++s) { \
            const int cb = s * 64 + kq; \
            bfx8 ah[4], al[4]; \
            _Pragma("unroll") \
            for (int m = 0; m < 4; ++m) { \
                const int off = (wm + m * 16 + fr) * 128 + (cb ^ frx); \
                ah[m] = *(const bfx8*)(base + off); \
                al[m] = *(const bfx8*)(base + 16384 + off); \
            } \
            _Pragma("unroll") \
            for (int n = 0; n < 4; ++n) { \
                const int off = (wn + n * 16 + fr) * 128 + (cb ^ frx); \
                bfx8 bh = *(const bfx8*)(base + 32768 + off); \
                bfx8 bl = *(const bfx8*)(base + 49152 + off); \
                _Pragma("unroll") \
                for (int m = 0; m < 4; ++m) { \
                    acc[m][n] = __builtin_amdgcn_mfma_f32_16x16x32_bf16(ah[m], bh, acc[m][n], 0, 0, 0); \
                    acc[m][n] = __builtin_amdgcn_mfma_f32_16x16x32_bf16(ah[m], bl, acc[m][n], 0, 0, 0); \
                    acc[m][n] = __builtin_amdgcn_mfma_f32_16x16x32_bf16(al[m], bh, acc[m][n], 0, 0, 0); \
                } \
            } \
        } }

    constexpr int NT = N / 64;
    STAGE(0, 0)
    __syncthreads();
    for (int kt = 0; kt < NT; ++kt) {
        const int cur = kt & 1;
        if (kt + 1 < NT) STAGE(cur ^ 1, kt + 1)
        COMPUTE(cur)
        __syncthreads();
    }

    // ---- epilogue 1: direct fragment stores of the (by,bx) tile ----
    float* Ct = (float*)&sm[0][0][0];            // [128][129] floats (64.5 KB)
    const int crow0 = (lane >> 4) * 4;
    #pragma unroll
    for (int m = 0; m < 4; ++m) {
        #pragma unroll
        for (int n = 0; n < 4; ++n) {
            #pragma unroll
            for (int r = 0; r < 4; ++r) {
                const int li = wm + m * 16 + crow0 + r;
                const int lj = wn + n * 16 + fr;
                float v = acc[m][n][r];
                if (MASKED) {
                    if (i0 + li != j0 + lj) v *= rowf[li] * colf[lj];
                }
                const size_t off = (size_t)(i0 + li) * N + j0 + lj;
                if (OMODE == 0) {
                    Cf[off] = v;
                } else {
                    u16 h = bf16_rne(v);
                    Cs[off]      = h;
                    Cs[NN + off] = bf16_rne(v - bf16_f(h));
                }
                if (SYMOUT) Ct[li * 129 + lj] = v;   // masked value staged
            }
        }
    }

    // ---- epilogue 2: mirrored tile (bx,by) via LDS bounce ----
    if (SYMOUT && by != bx) {
        __syncthreads();
        #pragma unroll
        for (int q = 0; q < 4; ++q) {
            const int idx2 = q * 256 + tid;       // 0..1023
            const int rr   = idx2 >> 3;           // output row j0+rr
            const int cc0  = (idx2 & 7) * 16;     // output col i0+cc0..+15
            float v[16];
            #pragma unroll
            for (int t = 0; t < 16; ++t) v[t] = Ct[(cc0 + t) * 129 + rr];
            const size_t off = (size_t)(j0 + rr) * N + i0 + cc0;
            if (OMODE == 0) {
                #pragma unroll
                for (int t = 0; t < 4; ++t)
                    *(float4*)(Cf + off + t * 4) =
                        make_float4(v[t*4], v[t*4+1], v[t*4+2], v[t*4+3]);
            } else {
                bfx8 hs[2], ls[2];
                #pragma unroll
                for (int t = 0; t < 16; ++t) {
                    u16 h = bf16_rne(v[t]);
                    hs[t >> 3][t & 7] = (short)h;
                    ls[t >> 3][t & 7] = (short)bf16_rne(v[t] - bf16_f(h));
                }
                *(bfx8*)(Cs + off)          = hs[0];
                *(bfx8*)(Cs + off + 8)      = hs[1];
                *(bfx8*)(Cs + NN + off)     = ls[0];
                *(bfx8*)(Cs + NN + off + 8) = ls[1];
            }
        }
    }
    #undef STAGE
    #undef COMPUTE
}

// ---------------------------------------------------------------------------
// Schedule:
//   slots: O1=Arec, O2=R, O3=D (d_out); W1=ws[0:16M), W2=ws[16M:32M)
//   1. A2 = split(A)                    -> W1u
//   2. RT = build_right (R^T fp32)      -> O3 (scratch)
//   3. R2 -> W2u, RT2 -> O1u, R fp32 -> O2   (from RT)
//   4. G1: Ts  = split(R2 (*) A2^T)     -> O3u  [full grid]
//   5. G2: D2  = split(mask(Ts (*) R2^T)) -> W1u [SYM: 136 blocks]
//   6. G3: T2s = split(RT2 (*) D2^T)    -> W2u  [full grid]
//   7. D fp32 = unsplit(D2)             -> O3
//   8. park RT2: O1u -> W1u (d2d)
//   9. G4: Arec = T2s (*) RT2^T         -> O1 fp32 [SYM: 136 blocks]
// ws requirement: 32 MB.
// ---------------------------------------------------------------------------
extern "C" void kernel_launch(void* const* d_in, const int* in_sizes, int n_in,
                              void* d_out, int out_size, void* d_ws, size_t ws_size,
                              hipStream_t stream) {
    const float* A     = (const float*)d_in[0];
    const float* O_all = (const float*)d_in[1];
    const int*   sel   = (const int*)d_in[2];
    const int*   wav   = (const int*)d_in[3];
    const int    Lw    = in_sizes[3];

    float* O1 = (float*)d_out;          // Arec slot
    float* O2 = O1 + NN;                // R slot
    float* O3 = O1 + 2 * NN;            // D slot

    u16*   W1u = (u16*)d_ws;                                  // ws[0,16M)
    u16*   W2u = (u16*)((char*)d_ws + 2 * NN * sizeof(u16));  // ws[16M,32M)
    u16*   O1u = (u16*)O1;              // Arec slot as u16 scratch (RT2)
    u16*   O3u = (u16*)O3;              // D slot as u16 scratch (Ts)

    const int SGRID = (int)(NN / (256 * 8));

    split_plain_k<<<SGRID, 256, 0, stream>>>(A, W1u);                    // A2 -> W1
    build_right_k<<<N / 4, 64, 0, stream>>>(O_all, sel, O3);             // RT -> O3
    split_rt_k<<<(N / 64) * (N / 64), 256, 0, stream>>>(O3, W2u, O1u, O2); // R2,RT2,R

    gemm_bf3<0, 1, 0><<<256, 256, 0, stream>>>(W2u, W1u, nullptr, O3u, nullptr, 0); // Ts  -> O3
    gemm_bf3<1, 1, 1><<<136, 256, 0, stream>>>(O3u, W2u, nullptr, W1u, wav, Lw);    // D2  -> W1 (sym)
    gemm_bf3<0, 1, 0><<<256, 256, 0, stream>>>(O1u, W1u, nullptr, W2u, nullptr, 0); // T2s -> W2
    unsplit_k<<<SGRID, 256, 0, stream>>>(W1u, O3);                                  // D fp32 -> O3
    hipMemcpyAsync(W1u, O1u, 2 * NN * sizeof(u16), hipMemcpyDeviceToDevice, stream); // park RT2
    gemm_bf3<0, 0, 1><<<136, 256, 0, stream>>>(W2u, W1u, O1, nullptr, nullptr, 0);  // Arec -> O1 (sym)
}